// Round 2
// baseline (329.507 us; speedup 1.0000x reference)
//
#include <hip/hip_runtime.h>
#include <hip/hip_bf16.h>

using f32x4  = __attribute__((ext_vector_type(4))) float;
using bf16x8 = __attribute__((ext_vector_type(8))) short;
typedef unsigned int u32;

__device__ __forceinline__ unsigned short f2bf(float f) {
  u32 u = __float_as_uint(f);
  u += 0x7FFFu + ((u >> 16) & 1u);          // round-to-nearest-even
  return (unsigned short)(u >> 16);
}

// Pre-pass: convert the four 128x128 fp32 weights to bf16, laid out so the
// main kernel's per-lane MFMA B-fragment load is one coalesced 16B load.
// Layout: wsT[m][kk*4+gg][col][j]  (j=0..7), element = W_m[(32*kk+8*gg+j)*128 + col]
__global__ __launch_bounds__(256) void cvt_weights(
    const float* __restrict__ Wq, const float* __restrict__ Wk,
    const float* __restrict__ Wv, const float* __restrict__ Wo,
    unsigned short* __restrict__ wsT)
{
  const int o = blockIdx.x * 256 + threadIdx.x;   // 0..16383
  const int j   = o & 7;
  const int col = (o >> 3) & 127;
  const int blk = o >> 10;                        // 0..15 : kk*4+gg
  const int kk  = blk >> 2;
  const int gg  = blk & 3;
  const int src = (32 * kk + 8 * gg + j) * 128 + col;
  wsT[o]             = f2bf(Wq[src]);
  wsT[16384 + o]     = f2bf(Wk[src]);
  wsT[32768 + o]     = f2bf(Wv[src]);
  wsT[49152 + o]     = f2bf(Wo[src]);
}

__global__ __launch_bounds__(256, 3) void laa_fused(
    const float* __restrict__ x, const void* __restrict__ maskp,
    const unsigned short* __restrict__ wsT,
    const float* __restrict__ bq, const float* __restrict__ bk,
    const float* __restrict__ bv, const float* __restrict__ bo,
    float* __restrict__ out, int n_tiles)
{
  constexpr int C = 128;
  __shared__ __align__(128) unsigned short Qlds[16 * 128];
  __shared__ __align__(128) unsigned short Klds[16 * 128];
  __shared__ __align__(128) unsigned short VTlds[128 * 24]; // [ch][row], stride 24
  __shared__ __align__(128) unsigned short Olds[2][16 * 128]; // double-buffered

  const int tid  = threadIdx.x;
  const int wave = tid >> 6;
  const int lane = tid & 63;
  const int c0   = lane & 15;
  const int g    = lane >> 4;

  // ---- mask dtype detection (byte vs int32 upload) ----
  const u32* mw = (const u32*)maskp;
  u32 det = 0;
  #pragma unroll
  for (int i = 0; i < 64; ++i) det |= mw[i];
  const bool mask_is_byte = (det & 0xFFFFFF00u) != 0u;
  const unsigned char* mb = (const unsigned char*)maskp;
  const int mshift = mask_is_byte ? 0 : 2;   // low byte of LE int32 == value

  // ---- per-wave bf16 weight B-fragments: one coalesced 16B load each ----
  bf16x8 wqf[2][4], wkf[2][4], wvf[2][4], wof[2][4];
  float bq2[2], bk2[2], bv2[2], bo2[2];
  #pragma unroll
  for (int t = 0; t < 2; ++t) {
    const int col = 16 * (2 * wave + t) + c0;
    bq2[t] = bq[col]; bk2[t] = bk[col]; bv2[t] = bv[col]; bo2[t] = bo[col];
    #pragma unroll
    for (int kk = 0; kk < 4; ++kk) {
      const int off = (kk * 4 + g) * 1024 + col * 8;
      wqf[t][kk] = *(const bf16x8*)(wsT + off);
      wkf[t][kk] = *(const bf16x8*)(wsT + 16384 + off);
      wvf[t][kk] = *(const bf16x8*)(wsT + 32768 + off);
      wof[t][kk] = *(const bf16x8*)(wsT + 49152 + off);
    }
  }

  const float scale = 0.17677669529663687f; // 1/sqrt(32)

  float4 xr[8];
  int mr[4];
  auto load_x = [&](int t) {
    const float* xt = x + (size_t)t * (16 * C) + c0 * C + 8 * g;
    #pragma unroll
    for (int kk = 0; kk < 4; ++kk) {
      const float4* p = reinterpret_cast<const float4*>(xt + 32 * kk);
      xr[2 * kk]     = p[0];
      xr[2 * kk + 1] = p[1];
    }
  };
  auto load_m = [&](int t) {
    const int rb = t * 16 + 4 * g;
    #pragma unroll
    for (int i = 0; i < 4; ++i)
      mr[i] = (int)mb[(size_t)(rb + i) << mshift];
  };

  int tile = blockIdx.x;
  if (tile < n_tiles) { load_x(tile); load_m(tile); }
  int pb = 0;

  for (; tile < n_tiles; tile += gridDim.x) {
    const int rowbase = tile * 16;

    // ---- consume prefetched x -> bf16 A-fragments; mask -> kvf ----
    bf16x8 af[4];
    #pragma unroll
    for (int kk = 0; kk < 4; ++kk) {
      float4 u0 = xr[2 * kk], u1 = xr[2 * kk + 1];
      bf16x8 a;
      a[0]=(short)f2bf(u0.x); a[1]=(short)f2bf(u0.y); a[2]=(short)f2bf(u0.z); a[3]=(short)f2bf(u0.w);
      a[4]=(short)f2bf(u1.x); a[5]=(short)f2bf(u1.y); a[6]=(short)f2bf(u1.z); a[7]=(short)f2bf(u1.w);
      af[kk] = a;
    }
    float kvf[4];
    #pragma unroll
    for (int i = 0; i < 4; ++i) kvf[i] = (mr[i] != 0) ? 1.0f : 0.0f;

    // ---- prefetch next tile (latency hides under this tile's compute) ----
    const int nxt = tile + (int)gridDim.x;
    if (nxt < n_tiles) { load_x(nxt); load_m(nxt); }

    // ---- QKV projections (bias preloaded into acc) ----
    f32x4 qa[2], ka[2], va[2];
    #pragma unroll
    for (int t = 0; t < 2; ++t) {
      qa[t] = f32x4{bq2[t], bq2[t], bq2[t], bq2[t]};
      ka[t] = f32x4{bk2[t], bk2[t], bk2[t], bk2[t]};
      va[t] = f32x4{bv2[t], bv2[t], bv2[t], bv2[t]};
    }
    #pragma unroll
    for (int kk = 0; kk < 4; ++kk) {
      #pragma unroll
      for (int t = 0; t < 2; ++t) {
        qa[t] = __builtin_amdgcn_mfma_f32_16x16x32_bf16(af[kk], wqf[t][kk], qa[t], 0, 0, 0);
        ka[t] = __builtin_amdgcn_mfma_f32_16x16x32_bf16(af[kk], wkf[t][kk], ka[t], 0, 0, 0);
        va[t] = __builtin_amdgcn_mfma_f32_16x16x32_bf16(af[kk], wvf[t][kk], va[t], 0, 0, 0);
      }
    }

    // ---- stage Q,K (swizzled) and V^T  (wave-private LDS slices) ----
    #pragma unroll
    for (int t = 0; t < 2; ++t) {
      const int ch = 16 * (2 * wave + t) + c0;
      #pragma unroll
      for (int i = 0; i < 4; ++i) {
        const int row = 4 * g + i;
        const int off = (row * 256 + ch * 2) ^ ((row & 7) << 4);
        *(unsigned short*)((char*)Qlds + off) = f2bf(qa[t][i] * scale);
        *(unsigned short*)((char*)Klds + off) = f2bf(ka[t][i]);
        VTlds[ch * 24 + row] = f2bf(va[t][i]);
      }
    }

    // ---- S^T = K_h * Q_h^T (head h = wave): keys 4g..4g+3 of query c0, in-lane ----
    const int hch = 32 * wave;
    bf16x8 kfrag, qfrag;
    {
      const int row = c0;
      const int chb = hch + 8 * g;
      const int off = (row * 256 + chb * 2) ^ ((row & 7) << 4);
      kfrag = *(const bf16x8*)((const char*)Klds + off);
      qfrag = *(const bf16x8*)((const char*)Qlds + off);
    }
    f32x4 stv = f32x4{0.f, 0.f, 0.f, 0.f};
    stv = __builtin_amdgcn_mfma_f32_16x16x32_bf16(kfrag, qfrag, stv, 0, 0, 0);

    // ---- in-lane masked softmax over the 4 keys ----
    float mx = -1e30f;
    #pragma unroll
    for (int i = 0; i < 4; ++i) if (kvf[i] > 0.f) mx = fmaxf(mx, stv[i]);
    float p[4]; float den = 0.f;
    #pragma unroll
    for (int i = 0; i < 4; ++i) {
      p[i] = (kvf[i] > 0.f && mx > -1e29f) ? __expf(stv[i] - mx) : 0.f;
      den += p[i];
    }
    const float inv = den > 0.f ? 1.0f / den : 0.f;
    const bool diag = ((c0 >> 2) == g);
    u32 p01 = 0u, p23 = 0u;
    if (diag) {
      p01 = (u32)f2bf(p[0] * inv) | ((u32)f2bf(p[1] * inv) << 16);
      p23 = (u32)f2bf(p[2] * inv) | ((u32)f2bf(p[3] * inv) << 16);
    }

    // ---- assemble P A-fragment via ds_bpermute ----
    const int srcA = ((2 * g) * 16 + c0) * 4;
    const int srcB = ((2 * g + 1) * 16 + c0) * 4;
    u32 w0 = (u32)__builtin_amdgcn_ds_bpermute(srcA, (int)p01);
    u32 w1 = (u32)__builtin_amdgcn_ds_bpermute(srcA, (int)p23);
    u32 w2 = (u32)__builtin_amdgcn_ds_bpermute(srcB, (int)p01);
    u32 w3 = (u32)__builtin_amdgcn_ds_bpermute(srcB, (int)p23);
    if (g >= 2) { w0 = 0u; w1 = 0u; w2 = 0u; w3 = 0u; }
    bf16x8 pfrag;
    pfrag[0] = (short)(w0 & 0xFFFFu); pfrag[1] = (short)(w0 >> 16);
    pfrag[2] = (short)(w1 & 0xFFFFu); pfrag[3] = (short)(w1 >> 16);
    pfrag[4] = (short)(w2 & 0xFFFFu); pfrag[5] = (short)(w2 >> 16);
    pfrag[6] = (short)(w3 & 0xFFFFu); pfrag[7] = (short)(w3 >> 16);

    // ---- PV ----
    f32x4 oa[2];
    oa[0] = f32x4{0.f,0.f,0.f,0.f}; oa[1] = f32x4{0.f,0.f,0.f,0.f};
    #pragma unroll
    for (int nt2 = 0; nt2 < 2; ++nt2) {
      bf16x8 vfrag;
      if (g < 2) {
        const int ch = hch + 16 * nt2 + c0;
        vfrag = *(const bf16x8*)(&VTlds[ch * 24 + 8 * g]);
      } else {
        vfrag[0]=0; vfrag[1]=0; vfrag[2]=0; vfrag[3]=0;
        vfrag[4]=0; vfrag[5]=0; vfrag[6]=0; vfrag[7]=0;
      }
      oa[nt2] = __builtin_amdgcn_mfma_f32_16x16x32_bf16(pfrag, vfrag, oa[nt2], 0, 0, 0);
    }

    // ---- stage O (crosses waves) into buffer pb ----
    unsigned short* Ob = &Olds[pb][0];
    #pragma unroll
    for (int nt2 = 0; nt2 < 2; ++nt2) {
      const int ch = hch + 16 * nt2 + c0;
      #pragma unroll
      for (int i = 0; i < 4; ++i) {
        const int row = 4 * g + i;
        const int off = (row * 256 + ch * 2) ^ ((row & 7) << 4);
        *(unsigned short*)((char*)Ob + off) = f2bf(oa[nt2][i]);
      }
    }
    __syncthreads();   // the ONLY barrier per tile (Olds double-buffered)

    // ---- final projection O @ Wo + bo ----
    bf16x8 of[4];
    #pragma unroll
    for (int kk = 0; kk < 4; ++kk) {
      const int row = c0;
      const int chb = 32 * kk + 8 * g;
      const int off = (row * 256 + chb * 2) ^ ((row & 7) << 4);
      of[kk] = *(const bf16x8*)((const char*)Ob + off);
    }
    f32x4 fa[2];
    #pragma unroll
    for (int t = 0; t < 2; ++t) fa[t] = f32x4{bo2[t], bo2[t], bo2[t], bo2[t]};
    #pragma unroll
    for (int kk = 0; kk < 4; ++kk) {
      #pragma unroll
      for (int t = 0; t < 2; ++t)
        fa[t] = __builtin_amdgcn_mfma_f32_16x16x32_bf16(of[kk], wof[t][kk], fa[t], 0, 0, 0);
    }

    // ---- store (zero fully-masked residues) ----
    const float rv = (kvf[0] + kvf[1] + kvf[2] + kvf[3]) > 0.f ? 1.0f : 0.f;
    #pragma unroll
    for (int t = 0; t < 2; ++t) {
      const int ch = 16 * (2 * wave + t) + c0;
      #pragma unroll
      for (int i = 0; i < 4; ++i) {
        const int row = rowbase + 4 * g + i;
        out[(size_t)row * C + ch] = fa[t][i] * rv;
      }
    }
    pb ^= 1;
  }
}

extern "C" void kernel_launch(void* const* d_in, const int* in_sizes, int n_in,
                              void* d_out, int out_size, void* d_ws, size_t ws_size,
                              hipStream_t stream) {
  (void)n_in; (void)ws_size; (void)out_size;
  const float* x  = (const float*)d_in[0];
  const void* mask = d_in[1];
  const float* Wq = (const float*)d_in[2];
  const float* bq = (const float*)d_in[3];
  const float* Wk = (const float*)d_in[4];
  const float* bk = (const float*)d_in[5];
  const float* Wv = (const float*)d_in[6];
  const float* bv = (const float*)d_in[7];
  const float* Wo = (const float*)d_in[8];
  const float* bo = (const float*)d_in[9];
  float* out = (float*)d_out;
  unsigned short* wsT = (unsigned short*)d_ws;

  hipLaunchKernelGGL(cvt_weights, dim3(64), dim3(256), 0, stream, Wq, Wk, Wv, Wo, wsT);

  const int rows = in_sizes[0] / 128;   // B*L*A
  const int n_tiles = rows / 16;
  int grid = n_tiles < 2048 ? n_tiles : 2048;
  hipLaunchKernelGGL(laa_fused, dim3(grid), dim3(256), 0, stream,
                     x, mask, wsT, bq, bk, bv, bo, out, n_tiles);
}

// Round 3
// 227.612 us; speedup vs baseline: 1.4477x; 1.4477x over previous
//
#include <hip/hip_runtime.h>
#include <hip/hip_bf16.h>

using f32x4  = __attribute__((ext_vector_type(4))) float;
using bf16x8 = __attribute__((ext_vector_type(8))) short;
typedef unsigned int u32;

__device__ __forceinline__ unsigned short f2bf(float f) {
  u32 u = __float_as_uint(f);
  u += 0x7FFFu + ((u >> 16) & 1u);          // round-to-nearest-even
  return (unsigned short)(u >> 16);
}

// Pre-pass: convert the four 128x128 fp32 weights to bf16, fragment-ordered:
// wsT[m][kk*4+gg][col][j] (j=0..7), element = W_m[(32*kk+8*gg+j)*128 + col]
__global__ __launch_bounds__(256) void cvt_weights(
    const float* __restrict__ Wq, const float* __restrict__ Wk,
    const float* __restrict__ Wv, const float* __restrict__ Wo,
    unsigned short* __restrict__ wsT)
{
  const int o = blockIdx.x * 256 + threadIdx.x;   // 0..16383
  const int j   = o & 7;
  const int col = (o >> 3) & 127;
  const int blk = o >> 10;                        // kk*4+gg
  const int kk  = blk >> 2;
  const int gg  = blk & 3;
  const int src = (32 * kk + 8 * gg + j) * 128 + col;
  wsT[o]             = f2bf(Wq[src]);
  wsT[16384 + o]     = f2bf(Wk[src]);
  wsT[32768 + o]     = f2bf(Wv[src]);
  wsT[49152 + o]     = f2bf(Wo[src]);
}

__global__ __launch_bounds__(256, 2) void laa_fused(
    const float* __restrict__ x, const void* __restrict__ maskp,
    const unsigned short* __restrict__ wsT,
    const float* __restrict__ bq, const float* __restrict__ bk,
    const float* __restrict__ bv, const float* __restrict__ bo,
    float* __restrict__ out, int n_tiles)
{
  constexpr int C = 128;
  // two tile-slots (u = 0/1) per iteration
  __shared__ __align__(128) unsigned short Qlds[2][16 * 128];
  __shared__ __align__(128) unsigned short Klds[2][16 * 128];
  __shared__ __align__(128) unsigned short VTlds[2][128 * 24];
  __shared__ __align__(128) unsigned short Olds[2][2][16 * 128]; // [parity][slot]

  const int tid  = threadIdx.x;
  const int wave = tid >> 6;
  const int lane = tid & 63;
  const int c0   = lane & 15;
  const int g    = lane >> 4;

  // ---- mask dtype detection (byte vs int32 upload) ----
  const u32* mw = (const u32*)maskp;
  u32 det = 0;
  #pragma unroll
  for (int i = 0; i < 64; ++i) det |= mw[i];
  const bool mask_is_byte = (det & 0xFFFFFF00u) != 0u;
  const unsigned char* mb = (const unsigned char*)maskp;
  const int mshift = mask_is_byte ? 0 : 2;   // low byte of LE int32 == value

  // ---- per-wave bf16 weight B-fragments: coalesced 16B loads, L2-resident ----
  bf16x8 wqf[2][4], wkf[2][4], wvf[2][4], wof[2][4];
  float bq2[2], bk2[2], bv2[2], bo2[2];
  #pragma unroll
  for (int t = 0; t < 2; ++t) {
    const int col = 16 * (2 * wave + t) + c0;
    bq2[t] = bq[col]; bk2[t] = bk[col]; bv2[t] = bv[col]; bo2[t] = bo[col];
    #pragma unroll
    for (int kk = 0; kk < 4; ++kk) {
      const int off = (kk * 4 + g) * 1024 + col * 8;
      wqf[t][kk] = *(const bf16x8*)(wsT + off);
      wkf[t][kk] = *(const bf16x8*)(wsT + 16384 + off);
      wvf[t][kk] = *(const bf16x8*)(wsT + 32768 + off);
      wof[t][kk] = *(const bf16x8*)(wsT + 49152 + off);
    }
  }

  const float scale = 0.17677669529663687f; // 1/sqrt(32)
  const int hch = 32 * wave;
  int par = 0;

  for (int pair = blockIdx.x; 2 * pair < n_tiles; pair += gridDim.x) {
    const int t0 = 2 * pair;
    const int t1c = (t0 + 1 < n_tiles) ? t0 + 1 : t0;   // clamped (n_tiles even in practice)
    const bool has1 = (t0 + 1 < n_tiles);

    // ---- issue both tiles' x loads (MLP), then convert ----
    float4 xr0[8], xr1[8];
    {
      const float* p0 = x + (size_t)t0  * (16 * C) + c0 * C + 8 * g;
      const float* p1 = x + (size_t)t1c * (16 * C) + c0 * C + 8 * g;
      #pragma unroll
      for (int kk = 0; kk < 4; ++kk) {
        const float4* q0 = reinterpret_cast<const float4*>(p0 + 32 * kk);
        const float4* q1 = reinterpret_cast<const float4*>(p1 + 32 * kk);
        xr0[2*kk] = q0[0]; xr0[2*kk+1] = q0[1];
        xr1[2*kk] = q1[0]; xr1[2*kk+1] = q1[1];
      }
    }
    int mr0[4], mr1[4];
    #pragma unroll
    for (int i = 0; i < 4; ++i) {
      mr0[i] = (int)mb[(size_t)(t0  * 16 + 4 * g + i) << mshift];
      mr1[i] = (int)mb[(size_t)(t1c * 16 + 4 * g + i) << mshift];
    }

    bf16x8 af0[4], af1[4];
    #pragma unroll
    for (int kk = 0; kk < 4; ++kk) {
      float4 u0 = xr0[2*kk], u1 = xr0[2*kk+1];
      bf16x8 a;
      a[0]=(short)f2bf(u0.x); a[1]=(short)f2bf(u0.y); a[2]=(short)f2bf(u0.z); a[3]=(short)f2bf(u0.w);
      a[4]=(short)f2bf(u1.x); a[5]=(short)f2bf(u1.y); a[6]=(short)f2bf(u1.z); a[7]=(short)f2bf(u1.w);
      af0[kk] = a;
      float4 v0 = xr1[2*kk], v1 = xr1[2*kk+1];
      bf16x8 b;
      b[0]=(short)f2bf(v0.x); b[1]=(short)f2bf(v0.y); b[2]=(short)f2bf(v0.z); b[3]=(short)f2bf(v0.w);
      b[4]=(short)f2bf(v1.x); b[5]=(short)f2bf(v1.y); b[6]=(short)f2bf(v1.z); b[7]=(short)f2bf(v1.w);
      af1[kk] = b;
    }

    float kvf0[4], kvf1[4];
    #pragma unroll
    for (int i = 0; i < 4; ++i) {
      kvf0[i] = (mr0[i] != 0) ? 1.0f : 0.0f;
      kvf1[i] = (mr1[i] != 0) ? 1.0f : 0.0f;
    }

    // ---- QKV projections for both tiles (interleaved for ILP) ----
    f32x4 qa0[2], ka0[2], va0[2], qa1[2], ka1[2], va1[2];
    #pragma unroll
    for (int t = 0; t < 2; ++t) {
      qa0[t] = f32x4{bq2[t],bq2[t],bq2[t],bq2[t]}; qa1[t] = qa0[t];
      ka0[t] = f32x4{bk2[t],bk2[t],bk2[t],bk2[t]}; ka1[t] = ka0[t];
      va0[t] = f32x4{bv2[t],bv2[t],bv2[t],bv2[t]}; va1[t] = va0[t];
    }
    #pragma unroll
    for (int kk = 0; kk < 4; ++kk) {
      #pragma unroll
      for (int t = 0; t < 2; ++t) {
        qa0[t] = __builtin_amdgcn_mfma_f32_16x16x32_bf16(af0[kk], wqf[t][kk], qa0[t], 0, 0, 0);
        qa1[t] = __builtin_amdgcn_mfma_f32_16x16x32_bf16(af1[kk], wqf[t][kk], qa1[t], 0, 0, 0);
        ka0[t] = __builtin_amdgcn_mfma_f32_16x16x32_bf16(af0[kk], wkf[t][kk], ka0[t], 0, 0, 0);
        ka1[t] = __builtin_amdgcn_mfma_f32_16x16x32_bf16(af1[kk], wkf[t][kk], ka1[t], 0, 0, 0);
        va0[t] = __builtin_amdgcn_mfma_f32_16x16x32_bf16(af0[kk], wvf[t][kk], va0[t], 0, 0, 0);
        va1[t] = __builtin_amdgcn_mfma_f32_16x16x32_bf16(af1[kk], wvf[t][kk], va1[t], 0, 0, 0);
      }
    }

    // ---- stage Q,K (swizzled) and V^T for both slots (wave-private) ----
    #pragma unroll
    for (int u = 0; u < 2; ++u) {
      unsigned short* Qb = &Qlds[u][0];
      unsigned short* Kb = &Klds[u][0];
      unsigned short* Vb = &VTlds[u][0];
      #pragma unroll
      for (int t = 0; t < 2; ++t) {
        const int ch = 16 * (2 * wave + t) + c0;
        #pragma unroll
        for (int i = 0; i < 4; ++i) {
          const int row = 4 * g + i;
          const int off = (row * 256 + ch * 2) ^ ((row & 7) << 4);
          const float qv = u ? qa1[t][i] : qa0[t][i];
          const float kv = u ? ka1[t][i] : ka0[t][i];
          const float vv = u ? va1[t][i] : va0[t][i];
          *(unsigned short*)((char*)Qb + off) = f2bf(qv * scale);
          *(unsigned short*)((char*)Kb + off) = f2bf(kv);
          Vb[ch * 24 + row] = f2bf(vv);
        }
      }
    }

    // ---- attention for both slots ----
    f32x4 oa[2][2];
    #pragma unroll
    for (int u = 0; u < 2; ++u) {
      const unsigned short* Qb = &Qlds[u][0];
      const unsigned short* Kb = &Klds[u][0];
      const unsigned short* Vb = &VTlds[u][0];
      const float* kvf = u ? kvf1 : kvf0;

      bf16x8 kfrag, qfrag;
      {
        const int row = c0;
        const int chb = hch + 8 * g;
        const int off = (row * 256 + chb * 2) ^ ((row & 7) << 4);
        kfrag = *(const bf16x8*)((const char*)Kb + off);
        qfrag = *(const bf16x8*)((const char*)Qb + off);
      }
      f32x4 stv = f32x4{0.f, 0.f, 0.f, 0.f};
      stv = __builtin_amdgcn_mfma_f32_16x16x32_bf16(kfrag, qfrag, stv, 0, 0, 0);

      float mx = -1e30f;
      #pragma unroll
      for (int i = 0; i < 4; ++i) if (kvf[i] > 0.f) mx = fmaxf(mx, stv[i]);
      float p[4]; float den = 0.f;
      #pragma unroll
      for (int i = 0; i < 4; ++i) {
        p[i] = (kvf[i] > 0.f && mx > -1e29f) ? __expf(stv[i] - mx) : 0.f;
        den += p[i];
      }
      const float inv = den > 0.f ? 1.0f / den : 0.f;
      const bool diag = ((c0 >> 2) == g);
      u32 p01 = 0u, p23 = 0u;
      if (diag) {
        p01 = (u32)f2bf(p[0] * inv) | ((u32)f2bf(p[1] * inv) << 16);
        p23 = (u32)f2bf(p[2] * inv) | ((u32)f2bf(p[3] * inv) << 16);
      }

      const int srcA = ((2 * g) * 16 + c0) * 4;
      const int srcB = ((2 * g + 1) * 16 + c0) * 4;
      u32 w0 = (u32)__builtin_amdgcn_ds_bpermute(srcA, (int)p01);
      u32 w1 = (u32)__builtin_amdgcn_ds_bpermute(srcA, (int)p23);
      u32 w2 = (u32)__builtin_amdgcn_ds_bpermute(srcB, (int)p01);
      u32 w3 = (u32)__builtin_amdgcn_ds_bpermute(srcB, (int)p23);
      if (g >= 2) { w0 = 0u; w1 = 0u; w2 = 0u; w3 = 0u; }
      bf16x8 pfrag;
      pfrag[0] = (short)(w0 & 0xFFFFu); pfrag[1] = (short)(w0 >> 16);
      pfrag[2] = (short)(w1 & 0xFFFFu); pfrag[3] = (short)(w1 >> 16);
      pfrag[4] = (short)(w2 & 0xFFFFu); pfrag[5] = (short)(w2 >> 16);
      pfrag[6] = (short)(w3 & 0xFFFFu); pfrag[7] = (short)(w3 >> 16);

      oa[u][0] = f32x4{0.f,0.f,0.f,0.f};
      oa[u][1] = f32x4{0.f,0.f,0.f,0.f};
      #pragma unroll
      for (int nt2 = 0; nt2 < 2; ++nt2) {
        bf16x8 vfrag;
        if (g < 2) {
          const int ch = hch + 16 * nt2 + c0;
          vfrag = *(const bf16x8*)(&Vb[ch * 24 + 8 * g]);
        } else {
          vfrag[0]=0; vfrag[1]=0; vfrag[2]=0; vfrag[3]=0;
          vfrag[4]=0; vfrag[5]=0; vfrag[6]=0; vfrag[7]=0;
        }
        oa[u][nt2] = __builtin_amdgcn_mfma_f32_16x16x32_bf16(pfrag, vfrag, oa[u][nt2], 0, 0, 0);
      }
    }

    // ---- stage O for both slots (crosses waves), parity buffers ----
    #pragma unroll
    for (int u = 0; u < 2; ++u) {
      unsigned short* Ob = &Olds[par][u][0];
      #pragma unroll
      for (int nt2 = 0; nt2 < 2; ++nt2) {
        const int ch = hch + 16 * nt2 + c0;
        #pragma unroll
        for (int i = 0; i < 4; ++i) {
          const int row = 4 * g + i;
          const int off = (row * 256 + ch * 2) ^ ((row & 7) << 4);
          *(unsigned short*)((char*)Ob + off) = f2bf(oa[u][nt2][i]);
        }
      }
    }
    __syncthreads();   // single barrier per 2 tiles

    // ---- final projection + store for both slots ----
    #pragma unroll
    for (int u = 0; u < 2; ++u) {
      const unsigned short* Ob = &Olds[par][u][0];
      bf16x8 of[4];
      #pragma unroll
      for (int kk = 0; kk < 4; ++kk) {
        const int row = c0;
        const int chb = 32 * kk + 8 * g;
        const int off = (row * 256 + chb * 2) ^ ((row & 7) << 4);
        of[kk] = *(const bf16x8*)((const char*)Ob + off);
      }
      f32x4 fa[2];
      #pragma unroll
      for (int t = 0; t < 2; ++t) fa[t] = f32x4{bo2[t],bo2[t],bo2[t],bo2[t]};
      #pragma unroll
      for (int kk = 0; kk < 4; ++kk) {
        #pragma unroll
        for (int t = 0; t < 2; ++t)
          fa[t] = __builtin_amdgcn_mfma_f32_16x16x32_bf16(of[kk], wof[t][kk], fa[t], 0, 0, 0);
      }

      const float* kvf = u ? kvf1 : kvf0;
      const float rv = (kvf[0] + kvf[1] + kvf[2] + kvf[3]) > 0.f ? 1.0f : 0.f;
      const int tt = u ? t1c : t0;
      if (u == 0 || has1) {
        #pragma unroll
        for (int t = 0; t < 2; ++t) {
          const int ch = 16 * (2 * wave + t) + c0;
          #pragma unroll
          for (int i = 0; i < 4; ++i) {
            const int row = tt * 16 + 4 * g + i;
            out[(size_t)row * C + ch] = fa[t][i] * rv;
          }
        }
      }
    }
    par ^= 1;
  }
}

extern "C" void kernel_launch(void* const* d_in, const int* in_sizes, int n_in,
                              void* d_out, int out_size, void* d_ws, size_t ws_size,
                              hipStream_t stream) {
  (void)n_in; (void)ws_size; (void)out_size;
  const float* x  = (const float*)d_in[0];
  const void* mask = d_in[1];
  const float* Wq = (const float*)d_in[2];
  const float* bq = (const float*)d_in[3];
  const float* Wk = (const float*)d_in[4];
  const float* bk = (const float*)d_in[5];
  const float* Wv = (const float*)d_in[6];
  const float* bv = (const float*)d_in[7];
  const float* Wo = (const float*)d_in[8];
  const float* bo = (const float*)d_in[9];
  float* out = (float*)d_out;
  unsigned short* wsT = (unsigned short*)d_ws;

  hipLaunchKernelGGL(cvt_weights, dim3(64), dim3(256), 0, stream, Wq, Wk, Wv, Wo, wsT);

  const int rows = in_sizes[0] / 128;   // B*L*A
  const int n_tiles = rows / 16;
  const int pairs = (n_tiles + 1) / 2;
  int grid = pairs < 2048 ? pairs : 2048;
  hipLaunchKernelGGL(laa_fused, dim3(grid), dim3(256), 0, stream,
                     x, mask, wsT, bq, bk, bv, bo, out, n_tiles);
}

// Round 4
// 175.290 us; speedup vs baseline: 1.8798x; 1.2985x over previous
//
#include <hip/hip_runtime.h>
#include <hip/hip_bf16.h>

using f32x4  = __attribute__((ext_vector_type(4))) float;
using bf16x8 = __attribute__((ext_vector_type(8))) short;
typedef unsigned int u32;

__device__ __forceinline__ unsigned short f2bf(float f) {
  u32 u = __float_as_uint(f);
  u += 0x7FFFu + ((u >> 16) & 1u);          // round-to-nearest-even
  return (unsigned short)(u >> 16);
}

// Pre-pass: convert the four 128x128 fp32 weights to bf16, fragment-ordered:
// wsT[m][kk*4+gg][col][j] (j=0..7), element = W_m[(32*kk+8*gg+j)*128 + col]
__global__ __launch_bounds__(256) void cvt_weights(
    const float* __restrict__ Wq, const float* __restrict__ Wk,
    const float* __restrict__ Wv, const float* __restrict__ Wo,
    unsigned short* __restrict__ wsT)
{
  const int o = blockIdx.x * 256 + threadIdx.x;   // 0..16383
  const int j   = o & 7;
  const int col = (o >> 3) & 127;
  const int blk = o >> 10;                        // kk*4+gg
  const int kk  = blk >> 2;
  const int gg  = blk & 3;
  const int src = (32 * kk + 8 * gg + j) * 128 + col;
  wsT[o]             = f2bf(Wq[src]);
  wsT[16384 + o]     = f2bf(Wk[src]);
  wsT[32768 + o]     = f2bf(Wv[src]);
  wsT[49152 + o]     = f2bf(Wo[src]);
}

__global__ __launch_bounds__(256) void laa_fused(
    const float* __restrict__ x, const void* __restrict__ maskp,
    const unsigned short* __restrict__ wsT,
    const float* __restrict__ bq, const float* __restrict__ bk,
    const float* __restrict__ bv, const float* __restrict__ bo,
    float* __restrict__ out, int n_tiles)
{
  constexpr int C = 128;
  __shared__ __align__(128) unsigned short Qlds[16 * 128];
  __shared__ __align__(128) unsigned short Klds[16 * 128];
  __shared__ __align__(128) unsigned short VTlds[128 * 24]; // [ch][row], stride 24
  __shared__ __align__(128) unsigned short Olds[2][16 * 128]; // parity dbuf

  const int tid  = threadIdx.x;
  const int wave = tid >> 6;
  const int lane = tid & 63;
  const int c0   = lane & 15;
  const int g    = lane >> 4;

  // ---- mask dtype detection (byte vs int32 upload) ----
  const u32* mw = (const u32*)maskp;
  u32 det = 0;
  #pragma unroll
  for (int i = 0; i < 64; ++i) det |= mw[i];
  const bool mask_is_byte = (det & 0xFFFFFF00u) != 0u;
  const unsigned char* mb = (const unsigned char*)maskp;
  const int mshift = mask_is_byte ? 0 : 2;   // low byte of LE int32 == value

  // ---- per-wave bf16 weight B-fragments: coalesced 16B loads, L2-resident ----
  bf16x8 wqf[2][4], wkf[2][4], wvf[2][4], wof[2][4];
  float bq2[2], bk2[2], bv2[2], bo2[2];
  #pragma unroll
  for (int t = 0; t < 2; ++t) {
    const int col = 16 * (2 * wave + t) + c0;
    bq2[t] = bq[col]; bk2[t] = bk[col]; bv2[t] = bv[col]; bo2[t] = bo[col];
    #pragma unroll
    for (int kk = 0; kk < 4; ++kk) {
      const int off = (kk * 4 + g) * 1024 + col * 8;
      wqf[t][kk] = *(const bf16x8*)(wsT + off);
      wkf[t][kk] = *(const bf16x8*)(wsT + 16384 + off);
      wvf[t][kk] = *(const bf16x8*)(wsT + 32768 + off);
      wof[t][kk] = *(const bf16x8*)(wsT + 49152 + off);
    }
  }

  const float scale = 0.17677669529663687f; // 1/sqrt(32)
  const int hch = 32 * wave;
  int par = 0;

  for (int tile = blockIdx.x; tile < n_tiles; tile += gridDim.x) {
    const int rowbase = tile * 16;
    const float* xt = x + (size_t)rowbase * C;

    // ---- x -> bf16 A-fragments ----
    bf16x8 af[4];
    #pragma unroll
    for (int kk = 0; kk < 4; ++kk) {
      const float4* p = reinterpret_cast<const float4*>(xt + c0 * C + 32 * kk + 8 * g);
      float4 u0 = p[0], u1 = p[1];
      bf16x8 a;
      a[0]=(short)f2bf(u0.x); a[1]=(short)f2bf(u0.y); a[2]=(short)f2bf(u0.z); a[3]=(short)f2bf(u0.w);
      a[4]=(short)f2bf(u1.x); a[5]=(short)f2bf(u1.y); a[6]=(short)f2bf(u1.z); a[7]=(short)f2bf(u1.w);
      af[kk] = a;
    }

    // ---- key mask for residue g of this tile ----
    float kvf[4];
    #pragma unroll
    for (int i = 0; i < 4; ++i) {
      const int idx = rowbase + 4 * g + i;
      kvf[i] = (mb[(size_t)idx << mshift] != 0) ? 1.0f : 0.0f;
    }

    // ---- QKV projections (bias preloaded into acc) ----
    f32x4 qa[2], ka[2], va[2];
    #pragma unroll
    for (int t = 0; t < 2; ++t) {
      qa[t] = f32x4{bq2[t], bq2[t], bq2[t], bq2[t]};
      ka[t] = f32x4{bk2[t], bk2[t], bk2[t], bk2[t]};
      va[t] = f32x4{bv2[t], bv2[t], bv2[t], bv2[t]};
    }
    #pragma unroll
    for (int kk = 0; kk < 4; ++kk) {
      #pragma unroll
      for (int t = 0; t < 2; ++t) {
        qa[t] = __builtin_amdgcn_mfma_f32_16x16x32_bf16(af[kk], wqf[t][kk], qa[t], 0, 0, 0);
        ka[t] = __builtin_amdgcn_mfma_f32_16x16x32_bf16(af[kk], wkf[t][kk], ka[t], 0, 0, 0);
        va[t] = __builtin_amdgcn_mfma_f32_16x16x32_bf16(af[kk], wvf[t][kk], va[t], 0, 0, 0);
      }
    }

    // ---- stage Q,K (swizzled) and V^T (wave-private LDS slices) ----
    #pragma unroll
    for (int t = 0; t < 2; ++t) {
      const int ch = 16 * (2 * wave + t) + c0;
      #pragma unroll
      for (int i = 0; i < 4; ++i) {
        const int row = 4 * g + i;
        const int off = (row * 256 + ch * 2) ^ ((row & 7) << 4);
        *(unsigned short*)((char*)Qlds + off) = f2bf(qa[t][i] * scale);
        *(unsigned short*)((char*)Klds + off) = f2bf(ka[t][i]);
        VTlds[ch * 24 + row] = f2bf(va[t][i]);
      }
    }

    // ---- S^T = K_h * Q_h^T (head h = wave): keys 4g..4g+3 of query c0, in-lane ----
    bf16x8 kfrag, qfrag;
    {
      const int row = c0;
      const int chb = hch + 8 * g;
      const int off = (row * 256 + chb * 2) ^ ((row & 7) << 4);
      kfrag = *(const bf16x8*)((const char*)Klds + off);
      qfrag = *(const bf16x8*)((const char*)Qlds + off);
    }
    f32x4 stv = f32x4{0.f, 0.f, 0.f, 0.f};
    stv = __builtin_amdgcn_mfma_f32_16x16x32_bf16(kfrag, qfrag, stv, 0, 0, 0);

    // ---- in-lane masked softmax over the 4 keys ----
    float mx = -1e30f;
    #pragma unroll
    for (int i = 0; i < 4; ++i) if (kvf[i] > 0.f) mx = fmaxf(mx, stv[i]);
    float p[4]; float den = 0.f;
    #pragma unroll
    for (int i = 0; i < 4; ++i) {
      p[i] = (kvf[i] > 0.f && mx > -1e29f) ? __expf(stv[i] - mx) : 0.f;
      den += p[i];
    }
    const float inv = den > 0.f ? 1.0f / den : 0.f;
    const bool diag = ((c0 >> 2) == g);
    u32 p01 = 0u, p23 = 0u;
    if (diag) {
      p01 = (u32)f2bf(p[0] * inv) | ((u32)f2bf(p[1] * inv) << 16);
      p23 = (u32)f2bf(p[2] * inv) | ((u32)f2bf(p[3] * inv) << 16);
    }

    // ---- assemble P A-fragment via ds_bpermute ----
    const int srcA = ((2 * g) * 16 + c0) * 4;
    const int srcB = ((2 * g + 1) * 16 + c0) * 4;
    u32 w0 = (u32)__builtin_amdgcn_ds_bpermute(srcA, (int)p01);
    u32 w1 = (u32)__builtin_amdgcn_ds_bpermute(srcA, (int)p23);
    u32 w2 = (u32)__builtin_amdgcn_ds_bpermute(srcB, (int)p01);
    u32 w3 = (u32)__builtin_amdgcn_ds_bpermute(srcB, (int)p23);
    if (g >= 2) { w0 = 0u; w1 = 0u; w2 = 0u; w3 = 0u; }
    bf16x8 pfrag;
    pfrag[0] = (short)(w0 & 0xFFFFu); pfrag[1] = (short)(w0 >> 16);
    pfrag[2] = (short)(w1 & 0xFFFFu); pfrag[3] = (short)(w1 >> 16);
    pfrag[4] = (short)(w2 & 0xFFFFu); pfrag[5] = (short)(w2 >> 16);
    pfrag[6] = (short)(w3 & 0xFFFFu); pfrag[7] = (short)(w3 >> 16);

    // ---- PV ----
    f32x4 oa[2];
    oa[0] = f32x4{0.f,0.f,0.f,0.f}; oa[1] = f32x4{0.f,0.f,0.f,0.f};
    #pragma unroll
    for (int nt2 = 0; nt2 < 2; ++nt2) {
      bf16x8 vfrag;
      if (g < 2) {
        const int ch = hch + 16 * nt2 + c0;
        vfrag = *(const bf16x8*)(&VTlds[ch * 24 + 8 * g]);
      } else {
        vfrag[0]=0; vfrag[1]=0; vfrag[2]=0; vfrag[3]=0;
        vfrag[4]=0; vfrag[5]=0; vfrag[6]=0; vfrag[7]=0;
      }
      oa[nt2] = __builtin_amdgcn_mfma_f32_16x16x32_bf16(pfrag, vfrag, oa[nt2], 0, 0, 0);
    }

    // ---- stage O (crosses waves) into parity buffer ----
    unsigned short* Ob = &Olds[par][0];
    #pragma unroll
    for (int nt2 = 0; nt2 < 2; ++nt2) {
      const int ch = hch + 16 * nt2 + c0;
      #pragma unroll
      for (int i = 0; i < 4; ++i) {
        const int row = 4 * g + i;
        const int off = (row * 256 + ch * 2) ^ ((row & 7) << 4);
        *(unsigned short*)((char*)Ob + off) = f2bf(oa[nt2][i]);
      }
    }
    __syncthreads();   // the ONLY barrier per tile (Olds parity-dbuf)

    // ---- final projection O @ Wo + bo ----
    bf16x8 of[4];
    #pragma unroll
    for (int kk = 0; kk < 4; ++kk) {
      const int row = c0;
      const int chb = 32 * kk + 8 * g;
      const int off = (row * 256 + chb * 2) ^ ((row & 7) << 4);
      of[kk] = *(const bf16x8*)((const char*)Ob + off);
    }
    f32x4 fa[2];
    #pragma unroll
    for (int t = 0; t < 2; ++t) fa[t] = f32x4{bo2[t], bo2[t], bo2[t], bo2[t]};
    #pragma unroll
    for (int kk = 0; kk < 4; ++kk) {
      #pragma unroll
      for (int t = 0; t < 2; ++t)
        fa[t] = __builtin_amdgcn_mfma_f32_16x16x32_bf16(of[kk], wof[t][kk], fa[t], 0, 0, 0);
    }

    // ---- store (zero fully-masked residues) ----
    const float rv = (kvf[0] + kvf[1] + kvf[2] + kvf[3]) > 0.f ? 1.0f : 0.f;
    #pragma unroll
    for (int t = 0; t < 2; ++t) {
      const int ch = 16 * (2 * wave + t) + c0;
      #pragma unroll
      for (int i = 0; i < 4; ++i) {
        const int row = rowbase + 4 * g + i;
        out[(size_t)row * C + ch] = fa[t][i] * rv;
      }
    }
    par ^= 1;
  }
}

extern "C" void kernel_launch(void* const* d_in, const int* in_sizes, int n_in,
                              void* d_out, int out_size, void* d_ws, size_t ws_size,
                              hipStream_t stream) {
  (void)n_in; (void)ws_size; (void)out_size;
  const float* x  = (const float*)d_in[0];
  const void* mask = d_in[1];
  const float* Wq = (const float*)d_in[2];
  const float* bq = (const float*)d_in[3];
  const float* Wk = (const float*)d_in[4];
  const float* bk = (const float*)d_in[5];
  const float* Wv = (const float*)d_in[6];
  const float* bv = (const float*)d_in[7];
  const float* Wo = (const float*)d_in[8];
  const float* bo = (const float*)d_in[9];
  float* out = (float*)d_out;
  unsigned short* wsT = (unsigned short*)d_ws;

  hipLaunchKernelGGL(cvt_weights, dim3(64), dim3(256), 0, stream, Wq, Wk, Wv, Wo, wsT);

  const int rows = in_sizes[0] / 128;   // B*L*A
  const int n_tiles = rows / 16;
  int grid = n_tiles < 2048 ? n_tiles : 2048;
  hipLaunchKernelGGL(laa_fused, dim3(grid), dim3(256), 0, stream,
                     x, mask, wsT, bq, bk, bv, bo, out, n_tiles);
}

// Round 5
// 164.272 us; speedup vs baseline: 2.0059x; 1.0671x over previous
//
#include <hip/hip_runtime.h>
#include <hip/hip_bf16.h>

using f32x4  = __attribute__((ext_vector_type(4))) float;
using bf16x8 = __attribute__((ext_vector_type(8))) short;
typedef unsigned int u32;
typedef unsigned short u16;

__device__ __forceinline__ u16 f2bf(float f) {
  u32 u = __float_as_uint(f);
  u += 0x7FFFu + ((u >> 16) & 1u);          // round-to-nearest-even
  return (u16)(u >> 16);
}

// Pre-pass: convert the four 128x128 fp32 weights to bf16, fragment-ordered:
// wsT[m][kk*4+gg][col][j] (j=0..7), element = W_m[(32*kk+8*gg+j)*128 + col]
__global__ __launch_bounds__(256) void cvt_weights(
    const float* __restrict__ Wq, const float* __restrict__ Wk,
    const float* __restrict__ Wv, const float* __restrict__ Wo,
    u16* __restrict__ wsT)
{
  const int o = blockIdx.x * 256 + threadIdx.x;   // 0..16383
  const int j   = o & 7;
  const int col = (o >> 3) & 127;
  const int blk = o >> 10;                        // kk*4+gg
  const int kk  = blk >> 2;
  const int gg  = blk & 3;
  const int src = (32 * kk + 8 * gg + j) * 128 + col;
  wsT[o]         = f2bf(Wq[src]);
  wsT[16384 + o] = f2bf(Wk[src]);
  wsT[32768 + o] = f2bf(Wv[src]);
  wsT[49152 + o] = f2bf(Wo[src]);
}

// One WAVE per 16-row tile. No __syncthreads anywhere: all LDS is wave-private.
__global__ __launch_bounds__(256) void laa_wave(
    const float* __restrict__ x, const void* __restrict__ maskp,
    const u16* __restrict__ wsT,
    const float* __restrict__ bq, const float* __restrict__ bk,
    const float* __restrict__ bv, const float* __restrict__ bo,
    float* __restrict__ out, int n_tiles)
{
  // per-wave private LDS slices
  __shared__ __align__(16) u16 QhL[4][16 * 40];   // [row][ch(32)+pad], stride 40 (80B, 16B-aligned reads)
  __shared__ __align__(16) u16 KhL[4][16 * 40];
  __shared__ __align__(16) u16 VTL[4][32 * 24];   // [ch][row+pad], stride 24 (48B)
  __shared__ __align__(16) u16 OTL[4][16 * 128];  // [row][ch], XOR-swizzled

  const int tid  = threadIdx.x;
  const int wave = tid >> 6;
  const int lane = tid & 63;
  const int c0   = lane & 15;
  const int g    = lane >> 4;

  u16* Qw = &QhL[wave][0];
  u16* Kw = &KhL[wave][0];
  u16* Vw = &VTL[wave][0];
  u16* Ow = &OTL[wave][0];

  // ---- mask dtype detection (byte vs int32 upload): 1 load + wave vote ----
  const u32 mv0 = ((const u32*)maskp)[lane];
  const bool mask_is_byte = __any((mv0 & 0xFFFFFF00u) != 0u);
  const unsigned char* mb = (const unsigned char*)maskp;
  const int mshift = mask_is_byte ? 0 : 2;   // low byte of LE int32 == value

  const float scale = 0.17677669529663687f;  // 1/sqrt(32)

  for (int tile = blockIdx.x * 4 + wave; tile < n_tiles; tile += (int)gridDim.x * 4) {
    const int rowbase = tile * 16;
    const float* xt = x + (size_t)rowbase * 128;

    // ---- x -> bf16 A-fragments (row c0, k = 32kk+8g+j) ----
    bf16x8 af[4];
    #pragma unroll
    for (int kk = 0; kk < 4; ++kk) {
      const float4* p = reinterpret_cast<const float4*>(xt + c0 * 128 + 32 * kk + 8 * g);
      float4 u0 = p[0], u1 = p[1];
      bf16x8 a;
      a[0]=(short)f2bf(u0.x); a[1]=(short)f2bf(u0.y); a[2]=(short)f2bf(u0.z); a[3]=(short)f2bf(u0.w);
      a[4]=(short)f2bf(u1.x); a[5]=(short)f2bf(u1.y); a[6]=(short)f2bf(u1.z); a[7]=(short)f2bf(u1.w);
      af[kk] = a;
    }

    // ---- key mask for residue g of this tile ----
    float kvf[4];
    #pragma unroll
    for (int i = 0; i < 4; ++i) {
      const int idx = rowbase + 4 * g + i;
      kvf[i] = (mb[(size_t)idx << mshift] != 0) ? 1.0f : 0.0f;
    }

    // ---- per-head: QKV projection + attention, O chunk -> wave-private OT ----
    #pragma unroll 1
    for (int h = 0; h < 4; ++h) {
      const int cb = 32 * h;

      f32x4 qa[2], ka[2], va[2];
      // --- Q projection (weights transient: 32 VGPRs) ---
      {
        bf16x8 w[2][4];
        #pragma unroll
        for (int t = 0; t < 2; ++t) {
          const int col = cb + 16 * t + c0;
          const float b = bq[col];
          qa[t] = f32x4{b, b, b, b};
          #pragma unroll
          for (int kk = 0; kk < 4; ++kk)
            w[t][kk] = *(const bf16x8*)(wsT + (kk * 4 + g) * 1024 + col * 8);
        }
        #pragma unroll
        for (int kk = 0; kk < 4; ++kk)
          #pragma unroll
          for (int t = 0; t < 2; ++t)
            qa[t] = __builtin_amdgcn_mfma_f32_16x16x32_bf16(af[kk], w[t][kk], qa[t], 0, 0, 0);
      }
      __builtin_amdgcn_sched_barrier(0);
      // --- K projection ---
      {
        bf16x8 w[2][4];
        #pragma unroll
        for (int t = 0; t < 2; ++t) {
          const int col = cb + 16 * t + c0;
          const float b = bk[col];
          ka[t] = f32x4{b, b, b, b};
          #pragma unroll
          for (int kk = 0; kk < 4; ++kk)
            w[t][kk] = *(const bf16x8*)(wsT + 16384 + (kk * 4 + g) * 1024 + col * 8);
        }
        #pragma unroll
        for (int kk = 0; kk < 4; ++kk)
          #pragma unroll
          for (int t = 0; t < 2; ++t)
            ka[t] = __builtin_amdgcn_mfma_f32_16x16x32_bf16(af[kk], w[t][kk], ka[t], 0, 0, 0);
      }
      __builtin_amdgcn_sched_barrier(0);
      // --- V projection ---
      {
        bf16x8 w[2][4];
        #pragma unroll
        for (int t = 0; t < 2; ++t) {
          const int col = cb + 16 * t + c0;
          const float b = bv[col];
          va[t] = f32x4{b, b, b, b};
          #pragma unroll
          for (int kk = 0; kk < 4; ++kk)
            w[t][kk] = *(const bf16x8*)(wsT + 32768 + (kk * 4 + g) * 1024 + col * 8);
        }
        #pragma unroll
        for (int kk = 0; kk < 4; ++kk)
          #pragma unroll
          for (int t = 0; t < 2; ++t)
            va[t] = __builtin_amdgcn_mfma_f32_16x16x32_bf16(af[kk], w[t][kk], va[t], 0, 0, 0);
      }
      __builtin_amdgcn_sched_barrier(0);

      // --- stage Q,K [row][lch] and V^T [lch][row] (lch = in-head channel) ---
      #pragma unroll
      for (int t = 0; t < 2; ++t) {
        const int lch = 16 * t + c0;
        #pragma unroll
        for (int i = 0; i < 4; ++i) {
          const int row = 4 * g + i;
          Qw[row * 40 + lch] = f2bf(qa[t][i] * scale);
          Kw[row * 40 + lch] = f2bf(ka[t][i]);
          Vw[lch * 24 + row] = f2bf(va[t][i]);
        }
      }

      // --- S^T = K_h * Q_h^T: lane holds keys 4g..4g+3 of query atom c0 ---
      bf16x8 kfrag = *(const bf16x8*)(Kw + c0 * 40 + 8 * g);
      bf16x8 qfrag = *(const bf16x8*)(Qw + c0 * 40 + 8 * g);
      f32x4 stv = f32x4{0.f, 0.f, 0.f, 0.f};
      stv = __builtin_amdgcn_mfma_f32_16x16x32_bf16(kfrag, qfrag, stv, 0, 0, 0);

      // --- in-lane masked softmax over the 4 keys ---
      float mx = -1e30f;
      #pragma unroll
      for (int i = 0; i < 4; ++i) if (kvf[i] > 0.f) mx = fmaxf(mx, stv[i]);
      float p[4]; float den = 0.f;
      #pragma unroll
      for (int i = 0; i < 4; ++i) {
        p[i] = (kvf[i] > 0.f && mx > -1e29f) ? __expf(stv[i] - mx) : 0.f;
        den += p[i];
      }
      const float inv = den > 0.f ? 1.0f / den : 0.f;
      const bool diag = ((c0 >> 2) == g);
      u32 p01 = 0u, p23 = 0u;
      if (diag) {
        p01 = (u32)f2bf(p[0] * inv) | ((u32)f2bf(p[1] * inv) << 16);
        p23 = (u32)f2bf(p[2] * inv) | ((u32)f2bf(p[3] * inv) << 16);
      }

      // --- assemble P A-fragment via ds_bpermute (within-wave) ---
      const int srcA = ((2 * g) * 16 + c0) * 4;
      const int srcB = ((2 * g + 1) * 16 + c0) * 4;
      u32 w0 = (u32)__builtin_amdgcn_ds_bpermute(srcA, (int)p01);
      u32 w1 = (u32)__builtin_amdgcn_ds_bpermute(srcA, (int)p23);
      u32 w2 = (u32)__builtin_amdgcn_ds_bpermute(srcB, (int)p01);
      u32 w3 = (u32)__builtin_amdgcn_ds_bpermute(srcB, (int)p23);
      if (g >= 2) { w0 = 0u; w1 = 0u; w2 = 0u; w3 = 0u; }
      bf16x8 pfrag;
      pfrag[0] = (short)(w0 & 0xFFFFu); pfrag[1] = (short)(w0 >> 16);
      pfrag[2] = (short)(w1 & 0xFFFFu); pfrag[3] = (short)(w1 >> 16);
      pfrag[4] = (short)(w2 & 0xFFFFu); pfrag[5] = (short)(w2 >> 16);
      pfrag[6] = (short)(w3 & 0xFFFFu); pfrag[7] = (short)(w3 >> 16);

      // --- PV; write this head's O chunk into wave-private OT ---
      #pragma unroll
      for (int nt2 = 0; nt2 < 2; ++nt2) {
        bf16x8 vfrag;
        if (g < 2) {
          vfrag = *(const bf16x8*)(Vw + (16 * nt2 + c0) * 24 + 8 * g);
        } else {
          vfrag[0]=0; vfrag[1]=0; vfrag[2]=0; vfrag[3]=0;
          vfrag[4]=0; vfrag[5]=0; vfrag[6]=0; vfrag[7]=0;
        }
        f32x4 oa = f32x4{0.f, 0.f, 0.f, 0.f};
        oa = __builtin_amdgcn_mfma_f32_16x16x32_bf16(pfrag, vfrag, oa, 0, 0, 0);
        const int ch = cb + 16 * nt2 + c0;
        #pragma unroll
        for (int i = 0; i < 4; ++i) {
          const int row = 4 * g + i;
          const int off = (row * 256 + ch * 2) ^ ((row & 7) << 4);
          *(u16*)((char*)Ow + off) = f2bf(oa[i]);
        }
      }
      __builtin_amdgcn_sched_barrier(0);
    }

    // ---- O-proj: read own OT, multiply by Wo, store ----
    bf16x8 of[4];
    #pragma unroll
    for (int kk = 0; kk < 4; ++kk) {
      const int off = (c0 * 256 + (32 * kk + 8 * g) * 2) ^ ((c0 & 7) << 4);
      of[kk] = *(const bf16x8*)((const char*)Ow + off);
    }
    const float rv = (kvf[0] + kvf[1] + kvf[2] + kvf[3]) > 0.f ? 1.0f : 0.f;

    #pragma unroll 4
    for (int colt = 0; colt < 8; ++colt) {
      const int col = 16 * colt + c0;
      const float b = bo[col];
      bf16x8 w[4];
      #pragma unroll
      for (int kk = 0; kk < 4; ++kk)
        w[kk] = *(const bf16x8*)(wsT + 49152 + (kk * 4 + g) * 1024 + col * 8);
      f32x4 fa = f32x4{b, b, b, b};
      #pragma unroll
      for (int kk = 0; kk < 4; ++kk)
        fa = __builtin_amdgcn_mfma_f32_16x16x32_bf16(of[kk], w[kk], fa, 0, 0, 0);
      #pragma unroll
      for (int i = 0; i < 4; ++i) {
        const int row = rowbase + 4 * g + i;
        out[(size_t)row * 128 + col] = fa[i] * rv;
      }
    }
  }
}

extern "C" void kernel_launch(void* const* d_in, const int* in_sizes, int n_in,
                              void* d_out, int out_size, void* d_ws, size_t ws_size,
                              hipStream_t stream) {
  (void)n_in; (void)ws_size; (void)out_size;
  const float* x  = (const float*)d_in[0];
  const void* mask = d_in[1];
  const float* Wq = (const float*)d_in[2];
  const float* bq = (const float*)d_in[3];
  const float* Wk = (const float*)d_in[4];
  const float* bk = (const float*)d_in[5];
  const float* Wv = (const float*)d_in[6];
  const float* bv = (const float*)d_in[7];
  const float* Wo = (const float*)d_in[8];
  const float* bo = (const float*)d_in[9];
  float* out = (float*)d_out;
  u16* wsT = (u16*)d_ws;

  hipLaunchKernelGGL(cvt_weights, dim3(64), dim3(256), 0, stream, Wq, Wk, Wv, Wo, wsT);

  const int rows = in_sizes[0] / 128;   // B*L*A
  const int n_tiles = rows / 16;
  const int wgs = (n_tiles + 3) / 4;
  int grid = wgs < 2048 ? wgs : 2048;
  hipLaunchKernelGGL(laa_wave, dim3(grid), dim3(256), 0, stream,
                     x, mask, wsT, bq, bk, bv, bo, out, n_tiles);
}

// Round 7
// 163.978 us; speedup vs baseline: 2.0095x; 1.0018x over previous
//
#include <hip/hip_runtime.h>
#include <hip/hip_bf16.h>

using f32x4  = __attribute__((ext_vector_type(4))) float;
using bf16x8 = __attribute__((ext_vector_type(8))) short;
typedef unsigned int u32;
typedef unsigned short u16;

__device__ __forceinline__ u32 pk2(float a, float b) {
  __hip_bfloat162 h = __float22bfloat162_rn(float2{a, b});   // v_cvt_pk_bf16_f32
  u32 r;
  __builtin_memcpy(&r, &h, 4);
  return r;
}
__device__ __forceinline__ u16 f2bf(float f) {
  u32 u = __float_as_uint(f);
  u += 0x7FFFu + ((u >> 16) & 1u);
  return (u16)(u >> 16);
}

// Pre-pass: four 128x128 fp32 weights -> bf16, fragment-ordered:
// wsT[m][kk*4+gg][col][j] (j=0..7), element = W_m[(32*kk+8*gg+j)*128 + col].
// Wq is pre-scaled by 1/sqrt(D) (folded attention scale).
__global__ __launch_bounds__(256) void cvt_weights(
    const float* __restrict__ Wq, const float* __restrict__ Wk,
    const float* __restrict__ Wv, const float* __restrict__ Wo,
    u16* __restrict__ wsT)
{
  const float scale = 0.17677669529663687f;  // 1/sqrt(32)
  const int o = blockIdx.x * 256 + threadIdx.x;   // 0..16383
  const int j   = o & 7;
  const int col = (o >> 3) & 127;
  const int blk = o >> 10;                        // kk*4+gg
  const int kk  = blk >> 2;
  const int gg  = blk & 3;
  const int src = (32 * kk + 8 * gg + j) * 128 + col;
  wsT[o]         = f2bf(Wq[src] * scale);
  wsT[16384 + o] = f2bf(Wk[src]);
  wsT[32768 + o] = f2bf(Wv[src]);
  wsT[49152 + o] = f2bf(Wo[src]);
}

// One WAVE per 16-row tile; all LDS wave-private, zero __syncthreads.
// Q^T/K^T via swapped-operand MFMA -> packed b64 staging; O^T likewise.
__global__ __launch_bounds__(256) void laa_wave(
    const float* __restrict__ x, const void* __restrict__ maskp,
    const u16* __restrict__ wsT,
    const float* __restrict__ bq, const float* __restrict__ bk,
    const float* __restrict__ bv, const float* __restrict__ bo,
    float* __restrict__ out, int n_tiles)
{
  __shared__ __align__(16) u16 QhL[4][16 * 40];   // [atom][ch0..31 +pad]
  __shared__ __align__(16) u16 KhL[4][16 * 40];
  __shared__ __align__(16) u16 VTL[4][32 * 24];   // [ch][atom +pad]
  __shared__ __align__(16) u16 OTL[4][16 * 128];  // [atom][ch], XOR-swizzled

  const int tid  = threadIdx.x;
  const int wave = tid >> 6;
  const int lane = tid & 63;
  const int c0   = lane & 15;
  const int g    = lane >> 4;

  u16* Qw = &QhL[wave][0];
  u16* Kw = &KhL[wave][0];
  u16* Vw = &VTL[wave][0];
  u16* Ow = &OTL[wave][0];

  // ---- mask dtype detection (byte vs int32 upload) ----
  const u32 mv0 = ((const u32*)maskp)[lane];
  const bool mask_is_byte = __any((mv0 & 0xFFFFFF00u) != 0u);
  const unsigned char* mb = (const unsigned char*)maskp;
  const int mshift = mask_is_byte ? 0 : 2;

  const float scale = 0.17677669529663687f;

  for (int tile = blockIdx.x * 4 + wave; tile < n_tiles; tile += (int)gridDim.x * 4) {
    const int rowbase = tile * 16;
    const float* xt = x + (size_t)rowbase * 128;

    // ---- x -> bf16 A-fragments (atom c0, ic = 32kk+8g+j) ----
    bf16x8 af[4];
    #pragma unroll
    for (int kk = 0; kk < 4; ++kk) {
      const float4* p = reinterpret_cast<const float4*>(xt + c0 * 128 + 32 * kk + 8 * g);
      float4 u0 = p[0], u1 = p[1];
      bf16x8 a;
      u32* ap = (u32*)&a;
      ap[0] = pk2(u0.x, u0.y); ap[1] = pk2(u0.z, u0.w);
      ap[2] = pk2(u1.x, u1.y); ap[3] = pk2(u1.z, u1.w);
      af[kk] = a;
    }

    // ---- key mask for residue g ----
    float kvf[4];
    #pragma unroll
    for (int i = 0; i < 4; ++i) {
      const int idx = rowbase + 4 * g + i;
      kvf[i] = (mb[(size_t)idx << mshift] != 0) ? 1.0f : 0.0f;
    }

    // ---- per-head pipeline ----
    #pragma unroll 1
    for (int h = 0; h < 4; ++h) {
      const int cb = 32 * h;

      // --- Q^T projection: qT[t] lane = Q[atom c0][ch cb+16t+4g+i] (scale folded in W,b) ---
      f32x4 qT[2], kT[2], va[2];
      {
        bf16x8 w[2][4];
        #pragma unroll
        for (int t = 0; t < 2; ++t) {
          float4 b4 = *(const float4*)(bq + cb + 16 * t + 4 * g);
          qT[t] = f32x4{b4.x * scale, b4.y * scale, b4.z * scale, b4.w * scale};
          #pragma unroll
          for (int kk = 0; kk < 4; ++kk)
            w[t][kk] = *(const bf16x8*)(wsT + (kk * 4 + g) * 1024 + (cb + 16 * t + c0) * 8);
        }
        #pragma unroll
        for (int kk = 0; kk < 4; ++kk)
          #pragma unroll
          for (int t = 0; t < 2; ++t)
            qT[t] = __builtin_amdgcn_mfma_f32_16x16x32_bf16(w[t][kk], af[kk], qT[t], 0, 0, 0);
      }
      __builtin_amdgcn_sched_barrier(0);
      // --- K^T projection ---
      {
        bf16x8 w[2][4];
        #pragma unroll
        for (int t = 0; t < 2; ++t) {
          float4 b4 = *(const float4*)(bk + cb + 16 * t + 4 * g);
          kT[t] = f32x4{b4.x, b4.y, b4.z, b4.w};
          #pragma unroll
          for (int kk = 0; kk < 4; ++kk)
            w[t][kk] = *(const bf16x8*)(wsT + 16384 + (kk * 4 + g) * 1024 + (cb + 16 * t + c0) * 8);
        }
        #pragma unroll
        for (int kk = 0; kk < 4; ++kk)
          #pragma unroll
          for (int t = 0; t < 2; ++t)
            kT[t] = __builtin_amdgcn_mfma_f32_16x16x32_bf16(w[t][kk], af[kk], kT[t], 0, 0, 0);
      }
      __builtin_amdgcn_sched_barrier(0);
      // --- V projection (normal order): va[t] lane = V[atom 4g+i][ch cb+16t+c0] ---
      {
        bf16x8 w[2][4];
        #pragma unroll
        for (int t = 0; t < 2; ++t) {
          const float b = bv[cb + 16 * t + c0];
          va[t] = f32x4{b, b, b, b};
          #pragma unroll
          for (int kk = 0; kk < 4; ++kk)
            w[t][kk] = *(const bf16x8*)(wsT + 32768 + (kk * 4 + g) * 1024 + (cb + 16 * t + c0) * 8);
        }
        #pragma unroll
        for (int kk = 0; kk < 4; ++kk)
          #pragma unroll
          for (int t = 0; t < 2; ++t)
            va[t] = __builtin_amdgcn_mfma_f32_16x16x32_bf16(af[kk], w[t][kk], va[t], 0, 0, 0);
      }
      __builtin_amdgcn_sched_barrier(0);

      // --- stage: all packed b64 writes ---
      #pragma unroll
      for (int t = 0; t < 2; ++t) {
        *(uint2*)(Qw + c0 * 40 + 16 * t + 4 * g) =
            uint2{pk2(qT[t][0], qT[t][1]), pk2(qT[t][2], qT[t][3])};
        *(uint2*)(Kw + c0 * 40 + 16 * t + 4 * g) =
            uint2{pk2(kT[t][0], kT[t][1]), pk2(kT[t][2], kT[t][3])};
        *(uint2*)(Vw + (16 * t + c0) * 24 + 4 * g) =
            uint2{pk2(va[t][0], va[t][1]), pk2(va[t][2], va[t][3])};
      }

      // --- S^T = K_h * Q_h^T: lane holds keys 4g..4g+3 of query atom c0 ---
      bf16x8 kfrag = *(const bf16x8*)(Kw + c0 * 40 + 8 * g);
      bf16x8 qfrag = *(const bf16x8*)(Qw + c0 * 40 + 8 * g);
      f32x4 stv = f32x4{0.f, 0.f, 0.f, 0.f};
      stv = __builtin_amdgcn_mfma_f32_16x16x32_bf16(kfrag, qfrag, stv, 0, 0, 0);

      // --- in-lane masked softmax over the 4 keys ---
      float mx = -1e30f;
      #pragma unroll
      for (int i = 0; i < 4; ++i) if (kvf[i] > 0.f) mx = fmaxf(mx, stv[i]);
      float p[4]; float den = 0.f;
      #pragma unroll
      for (int i = 0; i < 4; ++i) {
        p[i] = (kvf[i] > 0.f && mx > -1e29f) ? __expf(stv[i] - mx) : 0.f;
        den += p[i];
      }
      const float inv = den > 0.f ? 1.0f / den : 0.f;
      const bool diag = ((c0 >> 2) == g);
      u32 p01 = 0u, p23 = 0u;
      if (diag) {
        p01 = pk2(p[0] * inv, p[1] * inv);
        p23 = pk2(p[2] * inv, p[3] * inv);
      }

      // --- assemble P A/B-fragment via ds_bpermute ---
      const int srcA = ((2 * g) * 16 + c0) * 4;
      const int srcB = ((2 * g + 1) * 16 + c0) * 4;
      u32 w0 = (u32)__builtin_amdgcn_ds_bpermute(srcA, (int)p01);
      u32 w1 = (u32)__builtin_amdgcn_ds_bpermute(srcA, (int)p23);
      u32 w2 = (u32)__builtin_amdgcn_ds_bpermute(srcB, (int)p01);
      u32 w3 = (u32)__builtin_amdgcn_ds_bpermute(srcB, (int)p23);
      if (g >= 2) { w0 = 0u; w1 = 0u; w2 = 0u; w3 = 0u; }
      bf16x8 pfrag;
      {
        u32* pp = (u32*)&pfrag;
        pp[0] = w0; pp[1] = w1; pp[2] = w2; pp[3] = w3;
      }

      // --- O^T = V^T * P^T: lane gets O[atom c0][ch cb+16nt2+4g+i] -> b64 write ---
      #pragma unroll
      for (int nt2 = 0; nt2 < 2; ++nt2) {
        bf16x8 vfrag;
        if (g < 2) {
          vfrag = *(const bf16x8*)(Vw + (16 * nt2 + c0) * 24 + 8 * g);
        } else {
          vfrag[0]=0; vfrag[1]=0; vfrag[2]=0; vfrag[3]=0;
          vfrag[4]=0; vfrag[5]=0; vfrag[6]=0; vfrag[7]=0;
        }
        f32x4 ot = f32x4{0.f, 0.f, 0.f, 0.f};
        ot = __builtin_amdgcn_mfma_f32_16x16x32_bf16(vfrag, pfrag, ot, 0, 0, 0);
        const int off = (c0 * 256 + (cb + 16 * nt2 + 4 * g) * 2) ^ ((c0 & 7) << 4);
        *(uint2*)((char*)Ow + off) = uint2{pk2(ot[0], ot[1]), pk2(ot[2], ot[3])};
      }
      __builtin_amdgcn_sched_barrier(0);
    }

    // ---- O-proj: of[kk] = O[atom c0][ch 32kk+8g..+7], b128 swizzled reads ----
    bf16x8 of[4];
    #pragma unroll
    for (int kk = 0; kk < 4; ++kk) {
      const int off = (c0 * 256 + (32 * kk + 8 * g) * 2) ^ ((c0 & 7) << 4);
      of[kk] = *(const bf16x8*)((const char*)Ow + off);
    }
    const float rv = (kvf[0] + kvf[1] + kvf[2] + kvf[3]) > 0.f ? 1.0f : 0.f;

    #pragma unroll 4
    for (int colt = 0; colt < 8; ++colt) {
      const int col = 16 * colt + c0;
      const float b = bo[col];
      bf16x8 w[4];
      #pragma unroll
      for (int kk = 0; kk < 4; ++kk)
        w[kk] = *(const bf16x8*)(wsT + 49152 + (kk * 4 + g) * 1024 + col * 8);
      f32x4 fa = f32x4{b, b, b, b};
      #pragma unroll
      for (int kk = 0; kk < 4; ++kk)
        fa = __builtin_amdgcn_mfma_f32_16x16x32_bf16(of[kk], w[kk], fa, 0, 0, 0);
      #pragma unroll
      for (int i = 0; i < 4; ++i) {
        const int row = rowbase + 4 * g + i;
        out[(size_t)row * 128 + col] = fa[i] * rv;
      }
    }
  }
}

extern "C" void kernel_launch(void* const* d_in, const int* in_sizes, int n_in,
                              void* d_out, int out_size, void* d_ws, size_t ws_size,
                              hipStream_t stream) {
  (void)n_in; (void)ws_size; (void)out_size;
  const float* x  = (const float*)d_in[0];
  const void* mask = d_in[1];
  const float* Wq = (const float*)d_in[2];
  const float* bq = (const float*)d_in[3];
  const float* Wk = (const float*)d_in[4];
  const float* bk = (const float*)d_in[5];
  const float* Wv = (const float*)d_in[6];
  const float* bv = (const float*)d_in[7];
  const float* Wo = (const float*)d_in[8];
  const float* bo = (const float*)d_in[9];
  float* out = (float*)d_out;
  u16* wsT = (u16*)d_ws;

  hipLaunchKernelGGL(cvt_weights, dim3(64), dim3(256), 0, stream, Wq, Wk, Wv, Wo, wsT);

  const int rows = in_sizes[0] / 128;   // B*L*A
  const int n_tiles = rows / 16;
  const int wgs = (n_tiles + 3) / 4;
  int grid = wgs < 2048 ? wgs : 2048;
  hipLaunchKernelGGL(laa_wave, dim3(grid), dim3(256), 0, stream,
                     x, mask, wsT, bq, bk, bv, bo, out, n_tiles);
}